// Round 1
// baseline (1304.924 us; speedup 1.0000x reference)
//
#include <hip/hip_runtime.h>

// ---------------------------------------------------------------------------
// FullMHA: x(32,512,2048) fp32, w_qkv(6144,2048), w_out(2048,2048)
// qkv = x @ w_qkv^T ; RoPE(64) on q,k ; causal softmax(QK^T/sqrt(128))V ;
// out = y @ w_out^T.  All GEMMs in bf16 MFMA (16x16x32), fp32 accumulate.
// Workspace layout (~352 MB): cos/sin tables, bf16 casts of x/w_qkv/w_out,
// qkv bf16 (192 MB), y bf16 (64 MB).
// ---------------------------------------------------------------------------

typedef __bf16 bf16x8 __attribute__((ext_vector_type(8)));
typedef float floatx4 __attribute__((ext_vector_type(4)));

__device__ __forceinline__ unsigned short f2bf(float f) {
  union { float f; unsigned u; } v; v.f = f;
  unsigned r = v.u + 0x7FFFu + ((v.u >> 16) & 1u);   // RNE
  return (unsigned short)(r >> 16);
}
__device__ __forceinline__ float bf2f(unsigned short h) {
  union { unsigned u; float f; } v; v.u = ((unsigned)h) << 16; return v.f;
}

__device__ __forceinline__ void load_lds16(const void* g, void* l) {
  // async global->LDS, 16B/lane; LDS dest must be uniform base + lane*16
  __builtin_amdgcn_global_load_lds((__attribute__((address_space(1))) void*)g,
                                   (__attribute__((address_space(3))) void*)l,
                                   16, 0, 0);
}

// ---------------- RoPE tables: cos/sin[t][i], i=0..31, freq=10000^(-i/32) ---
__global__ void rope_tables(float* __restrict__ cost, float* __restrict__ sint) {
  int i = blockIdx.x * 256 + threadIdx.x;
  if (i >= 512 * 32) return;
  int t = i >> 5, f = i & 31;
  float e = -(float)(2 * f) / 64.0f;
  float freq = powf(10000.0f, e);
  float ang = (float)t * freq;
  cost[i] = cosf(ang);
  sint[i] = sinf(ang);
}

// ---------------- fp32 -> bf16 cast, 8 elems/thread ------------------------
__global__ void cast_bf16(const float* __restrict__ in,
                          unsigned short* __restrict__ out, int n8) {
  int i = blockIdx.x * 256 + threadIdx.x;
  if (i >= n8) return;
  float4 a = ((const float4*)in)[2 * i];
  float4 b = ((const float4*)in)[2 * i + 1];
  union { uint4 v; unsigned short u[8]; } o;
  o.u[0] = f2bf(a.x); o.u[1] = f2bf(a.y); o.u[2] = f2bf(a.z); o.u[3] = f2bf(a.w);
  o.u[4] = f2bf(b.x); o.u[5] = f2bf(b.y); o.u[6] = f2bf(b.z); o.u[7] = f2bf(b.w);
  ((uint4*)out)[i] = o.v;
}

// ---------------- GEMM: C[M,N] = A[M,K] * Bt[N,K]^T  (bf16 in, m97 recipe) --
// 128x128 tile, BK=64, 4 waves each 64x64 (4x4 mfma 16x16x32), async staging.
template <int OUT_BF16>
__global__ __launch_bounds__(256) void gemm_bt(
    const unsigned short* __restrict__ A, const unsigned short* __restrict__ Bt,
    void* __restrict__ Cout, int M, int N, int K) {
  __shared__ __align__(16) unsigned short As[128 * 64];
  __shared__ __align__(16) unsigned short Bs[128 * 64];
  const int tid = threadIdx.x;
  const int bn = blockIdx.x, bm = blockIdx.y;
  const int w = tid >> 6, l = tid & 63;
  const int quad = l >> 4, cl = l & 15;
  const int m_base = (w & 1) * 64, n_base = (w >> 1) * 64;
  floatx4 acc[4][4] = {};

  const int srow = tid >> 3;            // 0..31 staging row
  const int schunk = (tid & 7) * 8;     // bf16 offset in row
  const unsigned short* Ag = A + (size_t)(bm * 128 + srow) * K + schunk;
  const unsigned short* Bg = Bt + (size_t)(bn * 128 + srow) * K + schunk;
  unsigned short* asd = As + tid * 8;   // == uniform base + lane*16B
  unsigned short* bsd = Bs + tid * 8;

  for (int kt = 0; kt < K; kt += 64) {
    __syncthreads();
#pragma unroll
    for (int i = 0; i < 4; ++i) {
      load_lds16(Ag + (size_t)i * 32 * K + kt, asd + i * 32 * 64);
      load_lds16(Bg + (size_t)i * 32 * K + kt, bsd + i * 32 * 64);
    }
    __syncthreads();
#pragma unroll
    for (int k0 = 0; k0 < 64; k0 += 32) {
      bf16x8 a[4], b[4];
#pragma unroll
      for (int mt = 0; mt < 4; ++mt)
        a[mt] = *(const bf16x8*)(As + (m_base + mt * 16 + cl) * 64 + k0 + quad * 8);
#pragma unroll
      for (int nt = 0; nt < 4; ++nt)
        b[nt] = *(const bf16x8*)(Bs + (n_base + nt * 16 + cl) * 64 + k0 + quad * 8);
#pragma unroll
      for (int mt = 0; mt < 4; ++mt)
#pragma unroll
        for (int nt = 0; nt < 4; ++nt)
          acc[mt][nt] = __builtin_amdgcn_mfma_f32_16x16x32_bf16(
              a[mt], b[nt], acc[mt][nt], 0, 0, 0);
    }
  }
  // epilogue: C layout col=lane&15, row=quad*4+reg
#pragma unroll
  for (int mt = 0; mt < 4; ++mt)
#pragma unroll
    for (int nt = 0; nt < 4; ++nt)
#pragma unroll
      for (int r = 0; r < 4; ++r) {
        int gm = bm * 128 + m_base + mt * 16 + quad * 4 + r;
        int gn = bn * 128 + n_base + nt * 16 + cl;
        float v = acc[mt][nt][r];
        if (OUT_BF16)
          ((unsigned short*)Cout)[(size_t)gm * N + gn] = f2bf(v);
        else
          ((float*)Cout)[(size_t)gm * N + gn] = v;
      }
}

// ---------------- Fused RoPE + causal flash attention ----------------------
// grid (B*H=512, T/64=8). Block 256 = 4 waves; wave w owns q-rows [w*16,w*16+16).
// Per K-tile(64): S=QK^T via mfma (Q,K RoPE'd in LDS), online softmax in
// C-fragments, P->LDS (A-layout roundtrip), O += P V via mfma with V^T in LDS.
__global__ __launch_bounds__(256) void attn_kernel(
    const unsigned short* __restrict__ qkv, const float* __restrict__ cost,
    const float* __restrict__ sint, unsigned short* __restrict__ y) {
  __shared__ __align__(16) unsigned short Qs[64][136];
  __shared__ __align__(16) unsigned short Ks[64][136];
  __shared__ __align__(16) unsigned short VTs[128][72];
  __shared__ __align__(16) unsigned short Ps[4][16][72];

  const int bh = blockIdx.x, qt = blockIdx.y;
  const int b = bh >> 4, h = bh & 15;
  const int tid = threadIdx.x, w = tid >> 6, l = tid & 63;
  const int quad = l >> 4, cl = l & 15;
  const float scale = 0.08838834764831845f;  // 1/sqrt(128)

  // ---- Q tile load + RoPE + scale (folded into Q) ----
  {
    const int r = tid >> 2, j = tid & 3;  // 64 rows x 4 threads/row
    const int tg = qt * 64 + r;
    const unsigned short* qrow = qkv + (size_t)(b * 512 + tg) * 6144 + h * 128;
    union { uint4 v; unsigned short u[8]; } c1, c2, p1, p2;
    c1.v = *(const uint4*)(qrow + j * 8);         // x1: d in [j*8, j*8+8)
    c2.v = *(const uint4*)(qrow + j * 8 + 32);    // x2: d+32
    p1.v = *(const uint4*)(qrow + 64 + j * 16);   // passthrough
    p2.v = *(const uint4*)(qrow + 64 + j * 16 + 8);
#pragma unroll
    for (int jj = 0; jj < 8; ++jj) {
      int d = j * 8 + jj;
      float c = cost[tg * 32 + d], s = sint[tg * 32 + d];
      float x1 = bf2f(c1.u[jj]), x2 = bf2f(c2.u[jj]);
      Qs[r][d]      = f2bf((x1 * c - x2 * s) * scale);
      Qs[r][d + 32] = f2bf((x2 * c + x1 * s) * scale);
      Qs[r][64 + j * 16 + jj]     = f2bf(bf2f(p1.u[jj]) * scale);
      Qs[r][64 + j * 16 + 8 + jj] = f2bf(bf2f(p2.u[jj]) * scale);
    }
  }

  floatx4 o[8] = {};
  float m_i[4] = {-__builtin_inff(), -__builtin_inff(), -__builtin_inff(),
                  -__builtin_inff()};
  float l_i[4] = {0.f, 0.f, 0.f, 0.f};

  for (int ktile = 0; ktile <= qt; ++ktile) {
    __syncthreads();  // (A) previous PV done reading Ks/VTs
    {  // K tile load + RoPE (no scale)
      const int r = tid >> 2, j = tid & 3;
      const int tg = ktile * 64 + r;
      const unsigned short* krow =
          qkv + (size_t)(b * 512 + tg) * 6144 + 2048 + h * 128;
      union { uint4 v; unsigned short u[8]; } c1, c2, p1, p2;
      c1.v = *(const uint4*)(krow + j * 8);
      c2.v = *(const uint4*)(krow + j * 8 + 32);
      p1.v = *(const uint4*)(krow + 64 + j * 16);
      p2.v = *(const uint4*)(krow + 64 + j * 16 + 8);
#pragma unroll
      for (int jj = 0; jj < 8; ++jj) {
        int d = j * 8 + jj;
        float c = cost[tg * 32 + d], s = sint[tg * 32 + d];
        float x1 = bf2f(c1.u[jj]), x2 = bf2f(c2.u[jj]);
        Ks[r][d]      = f2bf(x1 * c - x2 * s);
        Ks[r][d + 32] = f2bf(x2 * c + x1 * s);
        Ks[r][64 + j * 16 + jj]     = p1.u[jj];
        Ks[r][64 + j * 16 + 8 + jj] = p2.u[jj];
      }
    }
    {  // V tile, transposed into VTs[d][kk]
#pragma unroll
      for (int i = 0; i < 16; ++i) {
        int idx = tid + i * 256;          // 0..4095 (uint pairs)
        int kk = idx >> 6;
        int dp = (idx & 63) * 2;
        const unsigned short* vrow =
            qkv + (size_t)(b * 512 + ktile * 64 + kk) * 6144 + 4096 + h * 128;
        unsigned int u = *(const unsigned int*)(vrow + dp);
        VTs[dp][kk] = (unsigned short)(u & 0xffffu);
        VTs[dp + 1][kk] = (unsigned short)(u >> 16);
      }
    }
    __syncthreads();  // (B) staging complete

    // S = Q K^T : wave w -> 16x64 strip
    floatx4 s[4] = {};
#pragma unroll
    for (int kc = 0; kc < 4; ++kc) {
      bf16x8 aq = *(const bf16x8*)(&Qs[w * 16 + cl][kc * 32 + quad * 8]);
#pragma unroll
      for (int nt = 0; nt < 4; ++nt) {
        bf16x8 bk = *(const bf16x8*)(&Ks[nt * 16 + cl][kc * 32 + quad * 8]);
        s[nt] = __builtin_amdgcn_mfma_f32_16x16x32_bf16(aq, bk, s[nt], 0, 0, 0);
      }
    }
    if (ktile == qt) {  // causal mask on diagonal tile
#pragma unroll
      for (int nt = 0; nt < 4; ++nt)
#pragma unroll
        for (int r = 0; r < 4; ++r) {
          int qrow_l = w * 16 + quad * 4 + r;
          int kcol_l = nt * 16 + cl;
          if (kcol_l > qrow_l) s[nt][r] = -__builtin_inff();
        }
    }
    // online softmax (rows live in reg index r, cols across 16 lanes of quad)
#pragma unroll
    for (int r = 0; r < 4; ++r) {
      float mx = fmaxf(fmaxf(s[0][r], s[1][r]), fmaxf(s[2][r], s[3][r]));
      mx = fmaxf(mx, __shfl_xor(mx, 1));
      mx = fmaxf(mx, __shfl_xor(mx, 2));
      mx = fmaxf(mx, __shfl_xor(mx, 4));
      mx = fmaxf(mx, __shfl_xor(mx, 8));
      float mn = fmaxf(m_i[r], mx);
      float a = expf(m_i[r] - mn);  // m_i=-inf,mn finite -> a=0, no NaN
      float rs = 0.f;
#pragma unroll
      for (int nt = 0; nt < 4; ++nt) {
        float p = expf(s[nt][r] - mn);
        s[nt][r] = p;
        rs += p;
      }
      rs += __shfl_xor(rs, 1);
      rs += __shfl_xor(rs, 2);
      rs += __shfl_xor(rs, 4);
      rs += __shfl_xor(rs, 8);
      l_i[r] = l_i[r] * a + rs;
      m_i[r] = mn;
#pragma unroll
      for (int nt2 = 0; nt2 < 8; ++nt2) o[nt2][r] *= a;
#pragma unroll
      for (int nt = 0; nt < 4; ++nt)
        Ps[w][quad * 4 + r][nt * 16 + cl] = f2bf(s[nt][r]);
    }
    __syncthreads();  // (C) P visible (and VTs still valid)

    // O += P V
#pragma unroll
    for (int kc2 = 0; kc2 < 2; ++kc2) {
      bf16x8 ap = *(const bf16x8*)(&Ps[w][cl][kc2 * 32 + quad * 8]);
#pragma unroll
      for (int nt2 = 0; nt2 < 8; ++nt2) {
        bf16x8 bv = *(const bf16x8*)(&VTs[nt2 * 16 + cl][kc2 * 32 + quad * 8]);
        o[nt2] = __builtin_amdgcn_mfma_f32_16x16x32_bf16(ap, bv, o[nt2], 0, 0, 0);
      }
    }
  }

  // epilogue: y[bt][h*128+d] = o/l  (the (B,H,T,D)->(B,T,C) transpose)
#pragma unroll
  for (int r = 0; r < 4; ++r) {
    float inv = 1.0f / l_i[r];
    size_t row =
        (size_t)(b * 512 + qt * 64 + w * 16 + quad * 4 + r) * 2048 + h * 128;
#pragma unroll
    for (int nt2 = 0; nt2 < 8; ++nt2)
      y[row + nt2 * 16 + cl] = f2bf(o[nt2][r] * inv);
  }
}

// ---------------------------------------------------------------------------
extern "C" void kernel_launch(void* const* d_in, const int* in_sizes, int n_in,
                              void* d_out, int out_size, void* d_ws,
                              size_t ws_size, hipStream_t stream) {
  const float* x = (const float*)d_in[0];
  const float* wqkv = (const float*)d_in[1];
  const float* wout = (const float*)d_in[2];
  float* out = (float*)d_out;

  char* ws = (char*)d_ws;
  float* cost = (float*)ws;            ws += (size_t)512 * 32 * 4;
  float* sint = (float*)ws;            ws += (size_t)512 * 32 * 4;
  unsigned short* xb = (unsigned short*)ws;    ws += (size_t)16384 * 2048 * 2;
  unsigned short* wqkvb = (unsigned short*)ws; ws += (size_t)6144 * 2048 * 2;
  unsigned short* woutb = (unsigned short*)ws; ws += (size_t)2048 * 2048 * 2;
  unsigned short* qkvb = (unsigned short*)ws;  ws += (size_t)16384 * 6144 * 2;
  unsigned short* yb = (unsigned short*)ws;    ws += (size_t)16384 * 2048 * 2;

  rope_tables<<<dim3(64), dim3(256), 0, stream>>>(cost, sint);
  cast_bf16<<<dim3(16384), dim3(256), 0, stream>>>(x, xb, 33554432 / 8);
  cast_bf16<<<dim3(6144), dim3(256), 0, stream>>>(wqkv, wqkvb, 12582912 / 8);
  cast_bf16<<<dim3(2048), dim3(256), 0, stream>>>(wout, woutb, 4194304 / 8);
  // qkv = x @ w_qkv^T  (M=16384, N=6144, K=2048), bf16 out
  gemm_bt<1><<<dim3(48, 128), dim3(256), 0, stream>>>(xb, wqkvb, (void*)qkvb,
                                                      16384, 6144, 2048);
  // fused RoPE + causal flash attention -> y (B,T,C) bf16
  attn_kernel<<<dim3(512, 8), dim3(256), 0, stream>>>(qkvb, cost, sint, yb);
  // out = y @ w_out^T (M=16384, N=2048, K=2048), fp32 out
  gemm_bt<0><<<dim3(16, 128), dim3(256), 0, stream>>>(yb, woutb, (void*)out,
                                                      16384, 2048, 2048);
}

// Round 2
// 1056.030 us; speedup vs baseline: 1.2357x; 1.2357x over previous
//
#include <hip/hip_runtime.h>

// ---------------------------------------------------------------------------
// FullMHA: x(32,512,2048) fp32, w_qkv(6144,2048), w_out(2048,2048)
// qkv = x @ w_qkv^T ; RoPE(64) on q,k ; causal softmax(QK^T/sqrt(128))V ;
// out = y @ w_out^T.  All GEMMs in bf16 MFMA (16x16x32), fp32 accumulate.
// R2: XOR-swizzled LDS tiles in gemm_bt (kills 1.5e8 bank conflicts);
//     attention staging vectorized (b128 writes) + swizzled V^T; exp2 softmax.
// ---------------------------------------------------------------------------

typedef __bf16 bf16x8 __attribute__((ext_vector_type(8)));
typedef float floatx4 __attribute__((ext_vector_type(4)));

__device__ __forceinline__ unsigned short f2bf(float f) {
  union { float f; unsigned u; } v; v.f = f;
  unsigned r = v.u + 0x7FFFu + ((v.u >> 16) & 1u);   // RNE
  return (unsigned short)(r >> 16);
}
__device__ __forceinline__ float bf2f(unsigned short h) {
  union { unsigned u; float f; } v; v.u = ((unsigned)h) << 16; return v.f;
}

__device__ __forceinline__ void load_lds16(const void* g, void* l) {
  __builtin_amdgcn_global_load_lds((__attribute__((address_space(1))) void*)g,
                                   (__attribute__((address_space(3))) void*)l,
                                   16, 0, 0);
}

// ---------------- RoPE tables ----------------------------------------------
__global__ void rope_tables(float* __restrict__ cost, float* __restrict__ sint) {
  int i = blockIdx.x * 256 + threadIdx.x;
  if (i >= 512 * 32) return;
  int t = i >> 5, f = i & 31;
  float e = -(float)(2 * f) / 64.0f;
  float freq = powf(10000.0f, e);
  float ang = (float)t * freq;
  cost[i] = cosf(ang);
  sint[i] = sinf(ang);
}

// ---------------- fp32 -> bf16 cast, 8 elems/thread ------------------------
__global__ void cast_bf16(const float* __restrict__ in,
                          unsigned short* __restrict__ out, int n8) {
  int i = blockIdx.x * 256 + threadIdx.x;
  if (i >= n8) return;
  float4 a = ((const float4*)in)[2 * i];
  float4 b = ((const float4*)in)[2 * i + 1];
  union { uint4 v; unsigned short u[8]; } o;
  o.u[0] = f2bf(a.x); o.u[1] = f2bf(a.y); o.u[2] = f2bf(a.z); o.u[3] = f2bf(a.w);
  o.u[4] = f2bf(b.x); o.u[5] = f2bf(b.y); o.u[6] = f2bf(b.z); o.u[7] = f2bf(b.w);
  ((uint4*)out)[i] = o.v;
}

// ---------------- GEMM: C[M,N] = A[M,K] * Bt[N,K]^T  (bf16, m97 + swizzle) --
// LDS tile [128][64]; 16B chunk c of row r stored at chunk c^(r&7).
// Staging: lane tid fetches global chunk (tid&7)^((tid>>3)&7) so the
// lane-ordered global_load_lds lands it at the swizzled slot.
template <int OUT_BF16>
__global__ __launch_bounds__(256) void gemm_bt(
    const unsigned short* __restrict__ A, const unsigned short* __restrict__ Bt,
    void* __restrict__ Cout, int M, int N, int K) {
  __shared__ __align__(16) unsigned short As[128 * 64];
  __shared__ __align__(16) unsigned short Bs[128 * 64];
  const int tid = threadIdx.x;
  const int bn = blockIdx.x, bm = blockIdx.y;
  const int w = tid >> 6, l = tid & 63;
  const int quad = l >> 4, cl = l & 15;
  const int m_base = (w & 1) * 64, n_base = (w >> 1) * 64;
  floatx4 acc[4][4] = {};

  const int srow = tid >> 3;                       // 0..31 staging row
  const int sc = (tid & 7) ^ (srow & 7);           // swizzled global chunk
  const unsigned short* Ag = A + (size_t)(bm * 128 + srow) * K + sc * 8;
  const unsigned short* Bg = Bt + (size_t)(bn * 128 + srow) * K + sc * 8;
  unsigned short* asd = As + tid * 8;
  unsigned short* bsd = Bs + tid * 8;

  for (int kt = 0; kt < K; kt += 64) {
    __syncthreads();
#pragma unroll
    for (int i = 0; i < 4; ++i) {
      load_lds16(Ag + (size_t)i * 32 * K + kt, asd + i * 32 * 64);
      load_lds16(Bg + (size_t)i * 32 * K + kt, bsd + i * 32 * 64);
    }
    __syncthreads();
#pragma unroll
    for (int k0 = 0; k0 < 64; k0 += 32) {
      const int xs = (((k0 >> 3) + quad) ^ (cl & 7)) << 3;  // swizzled offset
      bf16x8 a[4], b[4];
#pragma unroll
      for (int mt = 0; mt < 4; ++mt)
        a[mt] = *(const bf16x8*)(As + (m_base + mt * 16 + cl) * 64 + xs);
#pragma unroll
      for (int nt = 0; nt < 4; ++nt)
        b[nt] = *(const bf16x8*)(Bs + (n_base + nt * 16 + cl) * 64 + xs);
#pragma unroll
      for (int mt = 0; mt < 4; ++mt)
#pragma unroll
        for (int nt = 0; nt < 4; ++nt)
          acc[mt][nt] = __builtin_amdgcn_mfma_f32_16x16x32_bf16(
              a[mt], b[nt], acc[mt][nt], 0, 0, 0);
    }
  }
#pragma unroll
  for (int mt = 0; mt < 4; ++mt)
#pragma unroll
    for (int nt = 0; nt < 4; ++nt)
#pragma unroll
      for (int r = 0; r < 4; ++r) {
        int gm = bm * 128 + m_base + mt * 16 + quad * 4 + r;
        int gn = bn * 128 + n_base + nt * 16 + cl;
        float v = acc[mt][nt][r];
        if (OUT_BF16)
          ((unsigned short*)Cout)[(size_t)gm * N + gn] = f2bf(v);
        else
          ((float*)Cout)[(size_t)gm * N + gn] = v;
      }
}

// ---------------- Fused RoPE + causal flash attention ----------------------
// grid (B*H=512, T/64=8), 256 threads = 4 waves, wave w owns q-rows w*16..+16.
// Softmax kept in log2 domain: log2(e)/sqrt(128) folded into Q scale.
__global__ __launch_bounds__(256) void attn_kernel(
    const unsigned short* __restrict__ qkv, const float* __restrict__ cost,
    const float* __restrict__ sint, unsigned short* __restrict__ y) {
  __shared__ __align__(16) unsigned short Qs[64][136];
  __shared__ __align__(16) unsigned short Ks[64][136];
  __shared__ __align__(16) unsigned short VTs[128][64];  // chunk-swizzled
  __shared__ __align__(16) unsigned short Ps[4][16][72];

  const int bh = blockIdx.x, qt = blockIdx.y;
  const int b = bh >> 4, h = bh & 15;
  const int tid = threadIdx.x, w = tid >> 6, l = tid & 63;
  const int quad = l >> 4, cl = l & 15;
  // 1/sqrt(128) * log2(e)  (softmax in exp2 domain)
  const float scale = 0.08838834764831845f * 1.4426950408889634f;

  // ---- Q tile: load + RoPE + scale, vector LDS writes ----
  {
    const int r = tid >> 2, j = tid & 3;
    const int tg = qt * 64 + r;
    const unsigned short* qrow = qkv + (size_t)(b * 512 + tg) * 6144 + h * 128;
    union { uint4 v; unsigned short u[8]; } c1, c2, p1, p2, o1, o2, o3, o4;
    c1.v = *(const uint4*)(qrow + j * 8);
    c2.v = *(const uint4*)(qrow + j * 8 + 32);
    p1.v = *(const uint4*)(qrow + 64 + j * 16);
    p2.v = *(const uint4*)(qrow + 64 + j * 16 + 8);
#pragma unroll
    for (int jj = 0; jj < 8; ++jj) {
      int d = j * 8 + jj;
      float c = cost[tg * 32 + d], s = sint[tg * 32 + d];
      float x1 = bf2f(c1.u[jj]), x2 = bf2f(c2.u[jj]);
      o1.u[jj] = f2bf((x1 * c - x2 * s) * scale);
      o2.u[jj] = f2bf((x2 * c + x1 * s) * scale);
      o3.u[jj] = f2bf(bf2f(p1.u[jj]) * scale);
      o4.u[jj] = f2bf(bf2f(p2.u[jj]) * scale);
    }
    *(uint4*)&Qs[r][j * 8]          = o1.v;
    *(uint4*)&Qs[r][j * 8 + 32]     = o2.v;
    *(uint4*)&Qs[r][64 + j * 16]     = o3.v;
    *(uint4*)&Qs[r][64 + j * 16 + 8] = o4.v;
  }

  floatx4 o[8] = {};
  float m_i[4] = {-__builtin_inff(), -__builtin_inff(), -__builtin_inff(),
                  -__builtin_inff()};
  float l_i[4] = {0.f, 0.f, 0.f, 0.f};

  for (int ktile = 0; ktile <= qt; ++ktile) {
    __syncthreads();  // (A) previous PV done reading Ks/VTs
    {  // K tile: load + RoPE, vector LDS writes
      const int r = tid >> 2, j = tid & 3;
      const int tg = ktile * 64 + r;
      const unsigned short* krow =
          qkv + (size_t)(b * 512 + tg) * 6144 + 2048 + h * 128;
      union { uint4 v; unsigned short u[8]; } c1, c2, p1, p2, o1, o2;
      c1.v = *(const uint4*)(krow + j * 8);
      c2.v = *(const uint4*)(krow + j * 8 + 32);
      p1.v = *(const uint4*)(krow + 64 + j * 16);
      p2.v = *(const uint4*)(krow + 64 + j * 16 + 8);
#pragma unroll
      for (int jj = 0; jj < 8; ++jj) {
        int d = j * 8 + jj;
        float c = cost[tg * 32 + d], s = sint[tg * 32 + d];
        float x1 = bf2f(c1.u[jj]), x2 = bf2f(c2.u[jj]);
        o1.u[jj] = f2bf(x1 * c - x2 * s);
        o2.u[jj] = f2bf(x2 * c + x1 * s);
      }
      *(uint4*)&Ks[r][j * 8]          = o1.v;
      *(uint4*)&Ks[r][j * 8 + 32]     = o2.v;
      *(uint4*)&Ks[r][64 + j * 16]     = p1.v;
      *(uint4*)&Ks[r][64 + j * 16 + 8] = p2.v;
    }
    {  // V tile -> VTs[d][kk'], 8 kk-rows x 4 d-cols per thread, swizzled
      const int rowg = tid >> 5;        // kk0 = rowg*8
      const int colg = tid & 31;        // d0 = colg*4
      const int kk0 = rowg * 8, d0 = colg * 4;
      const unsigned short* vbase = qkv +
          (size_t)(b * 512 + ktile * 64 + kk0) * 6144 + 4096 + h * 128 + d0;
      uint2 rv[8];
#pragma unroll
      for (int rr = 0; rr < 8; ++rr)
        rv[rr] = *(const uint2*)(vbase + (size_t)rr * 6144);
#pragma unroll
      for (int c = 0; c < 4; ++c) {
        const int d = d0 + c;
        unsigned out[4];
#pragma unroll
        for (int p = 0; p < 4; ++p) {
          unsigned ua = ((const unsigned*)&rv[2 * p])[c >> 1];
          unsigned ub = ((const unsigned*)&rv[2 * p + 1])[c >> 1];
          unsigned lo = (c & 1) ? (ua >> 16) : (ua & 0xffffu);
          unsigned hi = (c & 1) ? (ub >> 16) : (ub & 0xffffu);
          out[p] = lo | (hi << 16);
        }
        *(uint4*)&VTs[d][(rowg ^ (d & 7)) << 3] = *(uint4*)out;
      }
    }
    __syncthreads();  // (B) staging complete

    // S = Q K^T : wave w -> 16x64 strip
    floatx4 s[4] = {};
#pragma unroll
    for (int kc = 0; kc < 4; ++kc) {
      bf16x8 aq = *(const bf16x8*)(&Qs[w * 16 + cl][kc * 32 + quad * 8]);
#pragma unroll
      for (int nt = 0; nt < 4; ++nt) {
        bf16x8 bk = *(const bf16x8*)(&Ks[nt * 16 + cl][kc * 32 + quad * 8]);
        s[nt] = __builtin_amdgcn_mfma_f32_16x16x32_bf16(aq, bk, s[nt], 0, 0, 0);
      }
    }
    if (ktile == qt) {  // causal mask on diagonal tile
#pragma unroll
      for (int nt = 0; nt < 4; ++nt)
#pragma unroll
        for (int r = 0; r < 4; ++r) {
          int qrow_l = w * 16 + quad * 4 + r;
          int kcol_l = nt * 16 + cl;
          if (kcol_l > qrow_l) s[nt][r] = -__builtin_inff();
        }
    }
    // online softmax (exp2 domain)
#pragma unroll
    for (int r = 0; r < 4; ++r) {
      float mx = fmaxf(fmaxf(s[0][r], s[1][r]), fmaxf(s[2][r], s[3][r]));
      mx = fmaxf(mx, __shfl_xor(mx, 1));
      mx = fmaxf(mx, __shfl_xor(mx, 2));
      mx = fmaxf(mx, __shfl_xor(mx, 4));
      mx = fmaxf(mx, __shfl_xor(mx, 8));
      float mn = fmaxf(m_i[r], mx);
      float a = exp2f(m_i[r] - mn);
      float rs = 0.f;
#pragma unroll
      for (int nt = 0; nt < 4; ++nt) {
        float p = exp2f(s[nt][r] - mn);
        s[nt][r] = p;
        rs += p;
      }
      rs += __shfl_xor(rs, 1);
      rs += __shfl_xor(rs, 2);
      rs += __shfl_xor(rs, 4);
      rs += __shfl_xor(rs, 8);
      l_i[r] = l_i[r] * a + rs;
      m_i[r] = mn;
#pragma unroll
      for (int nt2 = 0; nt2 < 8; ++nt2) o[nt2][r] *= a;
#pragma unroll
      for (int nt = 0; nt < 4; ++nt)
        Ps[w][quad * 4 + r][nt * 16 + cl] = f2bf(s[nt][r]);
    }
    __syncthreads();  // (C) P visible (VTs still valid)

    // O += P V  (B operand from swizzled VTs)
#pragma unroll
    for (int kc2 = 0; kc2 < 2; ++kc2) {
      bf16x8 ap = *(const bf16x8*)(&Ps[w][cl][kc2 * 32 + quad * 8]);
#pragma unroll
      for (int nt2 = 0; nt2 < 8; ++nt2) {
        bf16x8 bv = *(const bf16x8*)(
            &VTs[nt2 * 16 + cl][((kc2 * 4 + quad) ^ (cl & 7)) << 3]);
        o[nt2] = __builtin_amdgcn_mfma_f32_16x16x32_bf16(ap, bv, o[nt2], 0, 0, 0);
      }
    }
  }

  // epilogue: y[bt][h*128+d] = o/l
#pragma unroll
  for (int r = 0; r < 4; ++r) {
    float inv = 1.0f / l_i[r];
    size_t row =
        (size_t)(b * 512 + qt * 64 + w * 16 + quad * 4 + r) * 2048 + h * 128;
#pragma unroll
    for (int nt2 = 0; nt2 < 8; ++nt2)
      y[row + nt2 * 16 + cl] = f2bf(o[nt2][r] * inv);
  }
}

// ---------------------------------------------------------------------------
extern "C" void kernel_launch(void* const* d_in, const int* in_sizes, int n_in,
                              void* d_out, int out_size, void* d_ws,
                              size_t ws_size, hipStream_t stream) {
  const float* x = (const float*)d_in[0];
  const float* wqkv = (const float*)d_in[1];
  const float* wout = (const float*)d_in[2];
  float* out = (float*)d_out;

  char* ws = (char*)d_ws;
  float* cost = (float*)ws;            ws += (size_t)512 * 32 * 4;
  float* sint = (float*)ws;            ws += (size_t)512 * 32 * 4;
  unsigned short* xb = (unsigned short*)ws;    ws += (size_t)16384 * 2048 * 2;
  unsigned short* wqkvb = (unsigned short*)ws; ws += (size_t)6144 * 2048 * 2;
  unsigned short* woutb = (unsigned short*)ws; ws += (size_t)2048 * 2048 * 2;
  unsigned short* qkvb = (unsigned short*)ws;  ws += (size_t)16384 * 6144 * 2;
  unsigned short* yb = (unsigned short*)ws;    ws += (size_t)16384 * 2048 * 2;

  rope_tables<<<dim3(64), dim3(256), 0, stream>>>(cost, sint);
  cast_bf16<<<dim3(16384), dim3(256), 0, stream>>>(x, xb, 33554432 / 8);
  cast_bf16<<<dim3(6144), dim3(256), 0, stream>>>(wqkv, wqkvb, 12582912 / 8);
  cast_bf16<<<dim3(2048), dim3(256), 0, stream>>>(wout, woutb, 4194304 / 8);
  gemm_bt<1><<<dim3(48, 128), dim3(256), 0, stream>>>(xb, wqkvb, (void*)qkvb,
                                                      16384, 6144, 2048);
  attn_kernel<<<dim3(512, 8), dim3(256), 0, stream>>>(qkvb, cost, sint, yb);
  gemm_bt<0><<<dim3(16, 128), dim3(256), 0, stream>>>(yb, woutb, (void*)out,
                                                      16384, 2048, 2048);
}